// Round 8
// baseline (147.927 us; speedup 1.0000x reference)
//
#include <hip/hip_runtime.h>
#include <stdint.h>

#define B_SZ 2
#define T_SEQ 2048
#define D_MODEL 1024
#define NHEADS 16
#define HDIM 64
#define QKV_P (3 * D_MODEL) /* 3072 */

typedef unsigned short u16;
typedef uint32_t u32;
typedef __attribute__((ext_vector_type(4))) float f32x4;
typedef __attribute__((ext_vector_type(8))) short s16x8;

__device__ __forceinline__ u16 f2bf(float f) {
  union { float f; uint32_t u; } v; v.f = f;
  uint32_t r = v.u + 0x7fffu + ((v.u >> 16) & 1u);
  return (u16)(r >> 16);
}

__device__ __forceinline__ float fastexp2(float x) {
  float r;
  asm volatile("v_exp_f32 %0, %1" : "=v"(r) : "v"(x));
  return r;
}

__device__ __forceinline__ u32 cvtpk(float lo, float hi) {
  u32 r;
  asm volatile("v_cvt_pk_bf16_f32 %0, %1, %2" : "=v"(r) : "v"(lo), "v"(hi));
  return r;
}

__device__ __forceinline__ void async16(const void* g, void* l) {
  __builtin_amdgcn_global_load_lds((const __attribute__((address_space(1))) void*)g,
                                   (__attribute__((address_space(3))) void*)l,
                                   16, 0, 0);
}

// ---------------- fp32 -> bf16 convert (x) ----------------
__global__ void convert_bf16_kernel(const float* __restrict__ in, u16* __restrict__ out, int n4) {
  int i = blockIdx.x * blockDim.x + threadIdx.x;
  if (i < n4) {
    float4 v = ((const float4*)in)[i];
    ushort4 o;
    o.x = f2bf(v.x); o.y = f2bf(v.y); o.z = f2bf(v.z); o.w = f2bf(v.w);
    ((ushort4*)out)[i] = o;
  }
}

// ---------------- fp32 [R][C] -> bf16 [C][R] (weights) ----------------
__global__ void transpose_convert(const float* __restrict__ in, u16* __restrict__ out, int R, int C) {
  __shared__ float tile[32][33];
  const int tx = threadIdx.x, ty = threadIdx.y;
  const int c0 = blockIdx.x * 32, r0 = blockIdx.y * 32;
#pragma unroll
  for (int i = 0; i < 4; i++)
    tile[ty + i * 8][tx] = in[(size_t)(r0 + ty + i * 8) * C + c0 + tx];
  __syncthreads();
#pragma unroll
  for (int i = 0; i < 4; i++)
    out[(size_t)(c0 + ty + i * 8) * R + r0 + tx] = f2bf(tile[tx][ty + i * 8]);
}

// ---------------- V section of qkv -> VT[bh*64+hd][T] ----------------
__global__ void transpose_v(const u16* __restrict__ qkv, u16* __restrict__ vT) {
  __shared__ u16 tile[32][33];
  const int tx = threadIdx.x, ty = threadIdx.y;
  const int tt = blockIdx.x * 32;
  const int bh = blockIdx.y >> 1, hdt = blockIdx.y & 1;
  const int b = bh >> 4, h = bh & 15;
  const int hh = hdt * 32;
#pragma unroll
  for (int i = 0; i < 4; i++)
    tile[ty + i * 8][tx] =
        qkv[(size_t)(b * T_SEQ + tt + ty + i * 8) * QKV_P + 2 * D_MODEL + h * HDIM + hh + tx];
  __syncthreads();
#pragma unroll
  for (int i = 0; i < 4; i++)
    vT[(size_t)(bh * HDIM + hh + ty + i * 8) * T_SEQ + tt + tx] = tile[tx][ty + i * 8];
}

// ---------------- m97-style bf16 GEMM: C[M,N] = A[M,K] * BT[N,K]^T ----------------
template <int F32OUT>
__global__ __launch_bounds__(256) void gemm_bt(const u16* __restrict__ A,
                                               const u16* __restrict__ BT,
                                               void* __restrict__ Cout,
                                               int M, int N, int K) {
  __shared__ u16 As[128 * 32];
  __shared__ u16 Bs[128 * 32];
  const int tid = threadIdx.x;
  const int lane = tid & 63, w = tid >> 6;
  const int l15 = lane & 15, g = lane >> 4;
  const int wr = w >> 1, wc = w & 1;
  const int bn = blockIdx.x, bm = blockIdx.y;
  const u16* Ab = A + (size_t)bm * 128 * K;
  const u16* Bb = BT + (size_t)bn * 128 * K;
  f32x4 acc[4][4];
#pragma unroll
  for (int i = 0; i < 4; i++)
#pragma unroll
    for (int j = 0; j < 4; j++) acc[i][j] = (f32x4){0.f, 0.f, 0.f, 0.f};
  const int c0 = tid, c1 = tid + 256;
  for (int kt = 0; kt < K; kt += 32) {
    async16(Ab + (size_t)(c0 >> 2) * K + kt + (c0 & 3) * 8, (char*)As + c0 * 16);
    async16(Ab + (size_t)(c1 >> 2) * K + kt + (c1 & 3) * 8, (char*)As + c1 * 16);
    async16(Bb + (size_t)(c0 >> 2) * K + kt + (c0 & 3) * 8, (char*)Bs + c0 * 16);
    async16(Bb + (size_t)(c1 >> 2) * K + kt + (c1 & 3) * 8, (char*)Bs + c1 * 16);
    asm volatile("s_waitcnt vmcnt(0)" ::: "memory");
    __syncthreads();
    s16x8 af[4], bfr[4];
#pragma unroll
    for (int i = 0; i < 4; i++)
      af[i] = *(const s16x8*)(As + (wr * 64 + i * 16 + l15) * 32 + g * 8);
#pragma unroll
    for (int j = 0; j < 4; j++)
      bfr[j] = *(const s16x8*)(Bs + (wc * 64 + j * 16 + l15) * 32 + g * 8);
#pragma unroll
    for (int i = 0; i < 4; i++)
#pragma unroll
      for (int j = 0; j < 4; j++)
        acc[i][j] = __builtin_amdgcn_mfma_f32_16x16x32_bf16(af[i], bfr[j], acc[i][j], 0, 0, 0);
    __syncthreads();
  }
#pragma unroll
  for (int i = 0; i < 4; i++) {
    const int row0 = bm * 128 + wr * 64 + i * 16 + g * 4;
#pragma unroll
    for (int j = 0; j < 4; j++) {
      const int col = bn * 128 + wc * 64 + j * 16 + l15;
#pragma unroll
      for (int r = 0; r < 4; r++) {
        if (F32OUT)
          ((float*)Cout)[(size_t)(row0 + r) * N + col] = acc[i][j][r];
        else
          ((u16*)Cout)[(size_t)(row0 + r) * N + col] = f2bf(acc[i][j][r]);
      }
    }
  }
}

// ---------------- causal flash attention v8 ----------------
// 1024 blocks x 128 thr (2 waves). Each wave owns 32 q-rows (qc=0,1 x 16), so one
// K-frag/V-frag LDS read feeds 2 MFMAs (halves LDS-read redundancy vs 4x16 waves).
// Exactly 4 blocks/CU resident; per-CU strip sums balanced via magic-column map.
__global__ __launch_bounds__(128, 2) void flash_attn(const u16* __restrict__ qkv,
                                                     const u16* __restrict__ vT,
                                                     u16* __restrict__ attn) {
  __shared__ u16 Ks[2][64 * 64];  // [key][hd], XOR-swizzled
  __shared__ u16 Vs[2][64 * 64];  // [hd][key], XOR-swizzled
  const int tid = threadIdx.x;
  const int lane = tid & 63, w = tid >> 6;
  const int l15 = lane & 15, g = lane >> 4;
  const int id = blockIdx.x;
  const int bh = ((id & 7) << 2) | ((id >> 3) & 3);  // 4 heads per XCD
  // balanced strip map: per-CU sets {j, j+8, j+16, j+24} sum to 62; heavy-first
  const int j = (id >> 5) & 7, k4 = (id >> 8) & 3;
  const int qs = (k4 == 0) ? (31 - j) : (k4 == 1) ? (16 + j) : (k4 == 2) ? (15 - j) : j;
  const int b = bh >> 4, h = bh & 15;

  // Q fragments (B-layout: col = l15 = q-row, k = kk*32+g*8+j): qf[qc][kk]
  s16x8 qf[2][2];
#pragma unroll
  for (int qc = 0; qc < 2; qc++)
#pragma unroll
    for (int kk = 0; kk < 2; kk++)
      qf[qc][kk] = *(const s16x8*)(qkv +
                                   (size_t)(b * T_SEQ + qs * 64 + w * 32 + qc * 16 + l15) * QKV_P +
                                   h * HDIM + kk * 32 + g * 8);

  f32x4 O[2][4];  // O^T: lane holds O[hd = t*16+g*4+r][query = qc*16... via l15]
#pragma unroll
  for (int qc = 0; qc < 2; qc++)
#pragma unroll
    for (int t = 0; t < 4; t++) O[qc][t] = (f32x4){0.f, 0.f, 0.f, 0.f};
  float m_s[2] = {-1e30f, -1e30f}, l_s[2] = {0.f, 0.f};
  const float sc = 0.18033688011112042f;  // (1/sqrt(64)) * log2(e)
  const int lA = l15 + ((g & 1) << 5), hi = g >> 1;

  // stage one 64-key tile: 512 16B chunks each of K and VT, 8 async16/thread
#define STAGE(buf, kvt_)                                                                     \
  do {                                                                                       \
    _Pragma("unroll") for (int i_ = 0; i_ < 4; i_++) {                                       \
      int o_ = (tid + i_ * 128) * 16;                                                        \
      int lo_ = o_ ^ (((o_ >> 7) & 7) << 4);                                                 \
      int row_ = lo_ >> 7;                                                                   \
      int byt_ = lo_ & 127;                                                                  \
      async16(qkv + (size_t)(b * T_SEQ + (kvt_) * 64 + row_) * QKV_P + D_MODEL + h * HDIM +  \
                  (byt_ >> 1),                                                               \
              (char*)Ks[buf] + o_);                                                          \
      async16(vT + (size_t)(bh * HDIM + row_) * T_SEQ + (kvt_) * 64 + (byt_ >> 1),           \
              (char*)Vs[buf] + o_);                                                          \
    }                                                                                        \
  } while (0)

  STAGE(0, 0);
  int cur = 0;
  const int nt = qs + 1;
  for (int kvt = 0; kvt < nt; ++kvt) {
    if (kvt < qs) {
      STAGE(cur ^ 1, kvt + 1);
      asm volatile("s_waitcnt vmcnt(8)" ::: "memory");  // current tile's 8 loads done
    } else {
      asm volatile("s_waitcnt vmcnt(0)" ::: "memory");
    }
    __syncthreads();

    // S^T = K Q^T for both qc; each K-frag read feeds 2 MFMAs
    f32x4 S[2][4];
#pragma unroll
    for (int qc = 0; qc < 2; qc++)
#pragma unroll
      for (int t16 = 0; t16 < 4; t16++) S[qc][t16] = (f32x4){0.f, 0.f, 0.f, 0.f};
#pragma unroll
    for (int t16 = 0; t16 < 4; t16++)
#pragma unroll
      for (int kk = 0; kk < 2; kk++) {
        int key = t16 * 16 + l15;
        int bp = (key * 128 + kk * 64 + g * 16) ^ ((key & 7) << 4);
        s16x8 kf = *(const s16x8*)((const char*)Ks[cur] + bp);
        S[0][t16] = __builtin_amdgcn_mfma_f32_16x16x32_bf16(kf, qf[0][kk], S[0][t16], 0, 0, 0);
        S[1][t16] = __builtin_amdgcn_mfma_f32_16x16x32_bf16(kf, qf[1][kk], S[1][t16], 0, 0, 0);
      }

    const bool diag = (kvt == qs);
    u32 c[2][4][2];
#pragma unroll
    for (int qc = 0; qc < 2; qc++) {
      if (diag) {  // causal mask (raw units)
        const int qrl = w * 32 + qc * 16 + l15;
#pragma unroll
        for (int t16 = 0; t16 < 4; t16++)
#pragma unroll
          for (int r = 0; r < 4; r++)
            if (t16 * 16 + g * 4 + r > qrl) S[qc][t16][r] = -3e38f;
      }
      float mx = fmaxf(fmaxf(fmaxf(S[qc][0][0], S[qc][0][1]), fmaxf(S[qc][0][2], S[qc][0][3])),
                       fmaxf(fmaxf(S[qc][1][0], S[qc][1][1]), fmaxf(S[qc][1][2], S[qc][1][3])));
      mx = fmaxf(mx, fmaxf(fmaxf(fmaxf(S[qc][2][0], S[qc][2][1]), fmaxf(S[qc][2][2], S[qc][2][3])),
                           fmaxf(fmaxf(S[qc][3][0], S[qc][3][1]), fmaxf(S[qc][3][2], S[qc][3][3]))));
      mx = fmaxf(mx, __shfl_xor(mx, 16));
      mx = fmaxf(mx, __shfl_xor(mx, 32));
      const float mnew = fmaxf(m_s[qc], mx);
      const float alpha = fastexp2((m_s[qc] - mnew) * sc);
      m_s[qc] = mnew;
      const float msc = mnew * sc;
      float p[16];
#pragma unroll
      for (int t16 = 0; t16 < 4; t16++)
#pragma unroll
        for (int r = 0; r < 4; r++) p[t16 * 4 + r] = fastexp2(fmaf(S[qc][t16][r], sc, -msc));
      float ps = 0.f;
#pragma unroll
      for (int i = 0; i < 16; i++) ps += p[i];
      ps += __shfl_xor(ps, 16);
      ps += __shfl_xor(ps, 32);
      l_s[qc] = l_s[qc] * alpha + ps;
#pragma unroll
      for (int t = 0; t < 4; t++)
#pragma unroll
        for (int r = 0; r < 4; r++) O[qc][t][r] *= alpha;
      // pack P to bf16 pairs: c[qc][t16][q] = keys t16*16 + g*4 + {2q, 2q+1}
#pragma unroll
      for (int t16 = 0; t16 < 4; t16++) {
        c[qc][t16][0] = cvtpk(p[t16 * 4 + 0], p[t16 * 4 + 1]);
        c[qc][t16][1] = cvtpk(p[t16 * 4 + 2], p[t16 * 4 + 3]);
      }
    }

    // O^T += V^T P^T; each V-frag read feeds 2 MFMAs (qc=0,1)
#pragma unroll
    for (int kk = 0; kk < 2; kk++) {
      union { u32 u[4]; s16x8 v; } pu[2];
#pragma unroll
      for (int qc = 0; qc < 2; qc++) {
        u32 s00 = (u32)__shfl((int)c[qc][2 * kk][0], lA);
        u32 s01 = (u32)__shfl((int)c[qc][2 * kk][1], lA);
        u32 s10 = (u32)__shfl((int)c[qc][2 * kk + 1][0], lA);
        u32 s11 = (u32)__shfl((int)c[qc][2 * kk + 1][1], lA);
        u32 t00 = (u32)__shfl((int)c[qc][2 * kk][0], lA + 16);
        u32 t01 = (u32)__shfl((int)c[qc][2 * kk][1], lA + 16);
        u32 t10 = (u32)__shfl((int)c[qc][2 * kk + 1][0], lA + 16);
        u32 t11 = (u32)__shfl((int)c[qc][2 * kk + 1][1], lA + 16);
        pu[qc].u[0] = hi ? s10 : s00;
        pu[qc].u[1] = hi ? s11 : s01;
        pu[qc].u[2] = hi ? t10 : t00;
        pu[qc].u[3] = hi ? t11 : t01;
      }
#pragma unroll
      for (int t = 0; t < 4; t++) {
        int hd = t * 16 + l15;
        int bp = (hd * 128 + kk * 64 + g * 16) ^ ((hd & 7) << 4);
        s16x8 vf = *(const s16x8*)((const char*)Vs[cur] + bp);
        O[0][t] = __builtin_amdgcn_mfma_f32_16x16x32_bf16(vf, pu[0].v, O[0][t], 0, 0, 0);
        O[1][t] = __builtin_amdgcn_mfma_f32_16x16x32_bf16(vf, pu[1].v, O[1][t], 0, 0, 0);
      }
    }
    __syncthreads();
    cur ^= 1;
  }

#pragma unroll
  for (int qc = 0; qc < 2; qc++) {
    const float inv = 1.0f / l_s[qc];
    const size_t row = (size_t)(b * T_SEQ + qs * 64 + w * 32 + qc * 16 + l15);
#pragma unroll
    for (int t = 0; t < 4; t++)
#pragma unroll
      for (int pr = 0; pr < 2; pr++) {
        u32 pk = cvtpk(O[qc][t][pr * 2 + 0] * inv, O[qc][t][pr * 2 + 1] * inv);
        *(u32*)&attn[row * D_MODEL + h * HDIM + t * 16 + g * 4 + pr * 2] = pk;
      }
  }
}

extern "C" void kernel_launch(void* const* d_in, const int* in_sizes, int n_in,
                              void* d_out, int out_size, void* d_ws, size_t ws_size,
                              hipStream_t stream) {
  const float* x = (const float*)d_in[0];
  const float* w_qkv = (const float*)d_in[1];
  const float* w_proj = (const float*)d_in[2];
  float* out = (float*)d_out;
  char* ws = (char*)d_ws;
  const size_t MB = (size_t)1 << 20;
  if (ws_size < 56 * MB) return;  // need 56 MB scratch
  u16* xb = (u16*)(ws + 0);            // 8 MB  [4096][1024] bf16
  u16* wqkvT = (u16*)(ws + 8 * MB);    // 6 MB  [3072][1024] bf16
  u16* wprojT = (u16*)(ws + 14 * MB);  // 2 MB  [1024][1024] bf16
  u16* qkv = (u16*)(ws + 16 * MB);     // 24 MB [4096][3072] bf16
  u16* vT = (u16*)(ws + 40 * MB);      // 8 MB  [32*64][2048] bf16
  u16* attn = (u16*)(ws + 48 * MB);    // 8 MB  [4096][1024] bf16

  convert_bf16_kernel<<<4096, 256, 0, stream>>>(x, xb, (B_SZ * T_SEQ * D_MODEL) / 4);
  transpose_convert<<<dim3(96, 32), dim3(32, 8), 0, stream>>>(w_qkv, wqkvT, D_MODEL, QKV_P);
  transpose_convert<<<dim3(32, 32), dim3(32, 8), 0, stream>>>(w_proj, wprojT, D_MODEL, D_MODEL);
  gemm_bt<0><<<dim3(QKV_P / 128, (B_SZ * T_SEQ) / 128), 256, 0, stream>>>(
      xb, wqkvT, qkv, B_SZ * T_SEQ, QKV_P, D_MODEL);
  transpose_v<<<dim3(T_SEQ / 32, B_SZ * NHEADS * 2), dim3(32, 8), 0, stream>>>(qkv, vT);
  flash_attn<<<1024, 128, 0, stream>>>(qkv, vT, attn);
  gemm_bt<1><<<dim3(D_MODEL / 128, (B_SZ * T_SEQ) / 128), 256, 0, stream>>>(
      attn, wprojT, out, B_SZ * T_SEQ, D_MODEL, D_MODEL);
}

// Round 9
// 127.943 us; speedup vs baseline: 1.1562x; 1.1562x over previous
//
#include <hip/hip_runtime.h>
#include <stdint.h>

#define B_SZ 2
#define T_SEQ 2048
#define D_MODEL 1024
#define NHEADS 16
#define HDIM 64
#define QKV_P (3 * D_MODEL) /* 3072 */

typedef unsigned short u16;
typedef uint32_t u32;
typedef __attribute__((ext_vector_type(4))) float f32x4;
typedef __attribute__((ext_vector_type(8))) short s16x8;
typedef __attribute__((ext_vector_type(4))) short s16x4;

__device__ __forceinline__ u16 f2bf(float f) {
  union { float f; uint32_t u; } v; v.f = f;
  uint32_t r = v.u + 0x7fffu + ((v.u >> 16) & 1u);
  return (u16)(r >> 16);
}

__device__ __forceinline__ float fastexp2(float x) {
  float r;
  asm volatile("v_exp_f32 %0, %1" : "=v"(r) : "v"(x));
  return r;
}

__device__ __forceinline__ u32 cvtpk(float lo, float hi) {
  u32 r;
  asm volatile("v_cvt_pk_bf16_f32 %0, %1, %2" : "=v"(r) : "v"(lo), "v"(hi));
  return r;
}

__device__ __forceinline__ void async16(const void* g, void* l) {
  __builtin_amdgcn_global_load_lds((const __attribute__((address_space(1))) void*)g,
                                   (__attribute__((address_space(3))) void*)l,
                                   16, 0, 0);
}

// ---------------- fp32 -> bf16 convert (x) ----------------
__global__ void convert_bf16_kernel(const float* __restrict__ in, u16* __restrict__ out, int n4) {
  int i = blockIdx.x * blockDim.x + threadIdx.x;
  if (i < n4) {
    float4 v = ((const float4*)in)[i];
    ushort4 o;
    o.x = f2bf(v.x); o.y = f2bf(v.y); o.z = f2bf(v.z); o.w = f2bf(v.w);
    ((ushort4*)out)[i] = o;
  }
}

// ---------------- fp32 [R][C] -> bf16 [C][R] (weights) ----------------
__global__ void transpose_convert(const float* __restrict__ in, u16* __restrict__ out, int R, int C) {
  __shared__ float tile[32][33];
  const int tx = threadIdx.x, ty = threadIdx.y;
  const int c0 = blockIdx.x * 32, r0 = blockIdx.y * 32;
#pragma unroll
  for (int i = 0; i < 4; i++)
    tile[ty + i * 8][tx] = in[(size_t)(r0 + ty + i * 8) * C + c0 + tx];
  __syncthreads();
#pragma unroll
  for (int i = 0; i < 4; i++)
    out[(size_t)(c0 + ty + i * 8) * R + r0 + tx] = f2bf(tile[tx][ty + i * 8]);
}

// ---------------- V section of qkv -> VT[bh*64+hd][T] ----------------
__global__ void transpose_v(const u16* __restrict__ qkv, u16* __restrict__ vT) {
  __shared__ u16 tile[32][33];
  const int tx = threadIdx.x, ty = threadIdx.y;
  const int tt = blockIdx.x * 32;
  const int bh = blockIdx.y >> 1, hdt = blockIdx.y & 1;
  const int b = bh >> 4, h = bh & 15;
  const int hh = hdt * 32;
#pragma unroll
  for (int i = 0; i < 4; i++)
    tile[ty + i * 8][tx] =
        qkv[(size_t)(b * T_SEQ + tt + ty + i * 8) * QKV_P + 2 * D_MODEL + h * HDIM + hh + tx];
  __syncthreads();
#pragma unroll
  for (int i = 0; i < 4; i++)
    vT[(size_t)(bh * HDIM + hh + ty + i * 8) * T_SEQ + tt + tx] = tile[tx][ty + i * 8];
}

// ---------------- m97-style bf16 GEMM: C[M,N] = A[M,K] * BT[N,K]^T ----------------
template <int F32OUT>
__global__ __launch_bounds__(256) void gemm_bt(const u16* __restrict__ A,
                                               const u16* __restrict__ BT,
                                               void* __restrict__ Cout,
                                               int M, int N, int K) {
  __shared__ u16 As[128 * 32];
  __shared__ u16 Bs[128 * 32];
  const int tid = threadIdx.x;
  const int lane = tid & 63, w = tid >> 6;
  const int l15 = lane & 15, g = lane >> 4;
  const int wr = w >> 1, wc = w & 1;
  const int bn = blockIdx.x, bm = blockIdx.y;
  const u16* Ab = A + (size_t)bm * 128 * K;
  const u16* Bb = BT + (size_t)bn * 128 * K;
  f32x4 acc[4][4];
#pragma unroll
  for (int i = 0; i < 4; i++)
#pragma unroll
    for (int j = 0; j < 4; j++) acc[i][j] = (f32x4){0.f, 0.f, 0.f, 0.f};
  const int c0 = tid, c1 = tid + 256;
  for (int kt = 0; kt < K; kt += 32) {
    async16(Ab + (size_t)(c0 >> 2) * K + kt + (c0 & 3) * 8, (char*)As + c0 * 16);
    async16(Ab + (size_t)(c1 >> 2) * K + kt + (c1 & 3) * 8, (char*)As + c1 * 16);
    async16(Bb + (size_t)(c0 >> 2) * K + kt + (c0 & 3) * 8, (char*)Bs + c0 * 16);
    async16(Bb + (size_t)(c1 >> 2) * K + kt + (c1 & 3) * 8, (char*)Bs + c1 * 16);
    asm volatile("s_waitcnt vmcnt(0)" ::: "memory");
    __syncthreads();
    s16x8 af[4], bfr[4];
#pragma unroll
    for (int i = 0; i < 4; i++)
      af[i] = *(const s16x8*)(As + (wr * 64 + i * 16 + l15) * 32 + g * 8);
#pragma unroll
    for (int j = 0; j < 4; j++)
      bfr[j] = *(const s16x8*)(Bs + (wc * 64 + j * 16 + l15) * 32 + g * 8);
#pragma unroll
    for (int i = 0; i < 4; i++)
#pragma unroll
      for (int j = 0; j < 4; j++)
        acc[i][j] = __builtin_amdgcn_mfma_f32_16x16x32_bf16(af[i], bfr[j], acc[i][j], 0, 0, 0);
    __syncthreads();
  }
#pragma unroll
  for (int i = 0; i < 4; i++) {
    const int row0 = bm * 128 + wr * 64 + i * 16 + g * 4;
#pragma unroll
    for (int j = 0; j < 4; j++) {
      const int col = bn * 128 + wc * 64 + j * 16 + l15;
#pragma unroll
      for (int r = 0; r < 4; r++) {
        if (F32OUT)
          ((float*)Cout)[(size_t)(row0 + r) * N + col] = acc[i][j][r];
        else
          ((u16*)Cout)[(size_t)(row0 + r) * N + col] = f2bf(acc[i][j][r]);
      }
    }
  }
}

// ---------------- causal flash attention v9 ----------------
// r7 structure (1024 blocks x 256 thr, 4 waves x 16 q-rows, dbuf staging, vmcnt(4))
// + PV via mfma_f32_16x16x16bf16_1k: B-frag k-layout (g*4+j) == S/P C-layout, so the
//   cvtpk pairs feed PV directly -> the 16-bpermute/8-cndmask P-redistribution is GONE.
// + defer-max (T13): skip alpha/l/O rescale while max grows < 40 raw (~2^7.2 headroom).
__global__ __launch_bounds__(256, 3) void flash_attn(const u16* __restrict__ qkv,
                                                     const u16* __restrict__ vT,
                                                     u16* __restrict__ attn) {
  __shared__ u16 Ks[2][64 * 64];  // [key][hd], XOR-swizzled
  __shared__ u16 Vs[2][64 * 64];  // [hd][key], XOR-swizzled
  const int tid = threadIdx.x;
  const int lane = tid & 63, w = tid >> 6;
  const int l15 = lane & 15, g = lane >> 4;
  const int id = blockIdx.x;
  const int bh = ((id & 7) << 2) | ((id >> 3) & 3);  // 4 heads per XCD
  const int qs = 31 - (id >> 5);                     // 64-row strip, heavy-first
  const int b = bh >> 4, h = bh & 15;

  // Q fragments (B-layout: col = l15 = q-row, k = kk*32+g*8+j)
  const size_t qrow = (size_t)(b * T_SEQ + qs * 64 + w * 16 + l15);
  s16x8 qf[2];
  qf[0] = *(const s16x8*)(qkv + qrow * QKV_P + h * HDIM + 0 * 32 + g * 8);
  qf[1] = *(const s16x8*)(qkv + qrow * QKV_P + h * HDIM + 1 * 32 + g * 8);

  f32x4 O[4];  // O^T: lane holds O[hd = t*16+g*4+r][query = l15]
#pragma unroll
  for (int t = 0; t < 4; t++) O[t] = (f32x4){0.f, 0.f, 0.f, 0.f};
  float m_s = -1e30f, l_s = 0.f;          // raw-score units
  const int qrl = w * 16 + l15;           // q-row within strip
  const float sc = 0.18033688011112042f;  // (1/sqrt(64)) * log2(e)

#define STAGE(buf, kvt_)                                                                     \
  do {                                                                                       \
    _Pragma("unroll") for (int i_ = 0; i_ < 2; i_++) {                                       \
      int o_ = (tid + i_ * 256) * 16;                                                        \
      int lo_ = o_ ^ (((o_ >> 7) & 7) << 4);                                                 \
      int row_ = lo_ >> 7;                                                                   \
      int byt_ = lo_ & 127;                                                                  \
      async16(qkv + (size_t)(b * T_SEQ + (kvt_) * 64 + row_) * QKV_P + D_MODEL + h * HDIM +  \
                  (byt_ >> 1),                                                               \
              (char*)Ks[buf] + o_);                                                          \
      async16(vT + (size_t)(bh * HDIM + row_) * T_SEQ + (kvt_) * 64 + (byt_ >> 1),           \
              (char*)Vs[buf] + o_);                                                          \
    }                                                                                        \
  } while (0)

  STAGE(0, 0);
  int cur = 0;
  const int nt = qs + 1;
  for (int kvt = 0; kvt < nt; ++kvt) {
    if (kvt < qs) {
      STAGE(cur ^ 1, kvt + 1);
      asm volatile("s_waitcnt vmcnt(4)" ::: "memory");
    } else {
      asm volatile("s_waitcnt vmcnt(0)" ::: "memory");
    }
    __syncthreads();

    // S^T = K Q^T: lane (l15,g) holds S[query=l15][key = t16*16+g*4+r]
    f32x4 S[4];
#pragma unroll
    for (int t16 = 0; t16 < 4; t16++) S[t16] = (f32x4){0.f, 0.f, 0.f, 0.f};
#pragma unroll
    for (int t16 = 0; t16 < 4; t16++)
#pragma unroll
      for (int kk = 0; kk < 2; kk++) {
        int key = t16 * 16 + l15;
        int bp = (key * 128 + kk * 64 + g * 16) ^ ((key & 7) << 4);
        s16x8 kf = *(const s16x8*)((const char*)Ks[cur] + bp);
        S[t16] = __builtin_amdgcn_mfma_f32_16x16x32_bf16(kf, qf[kk], S[t16], 0, 0, 0);
      }

    if (kvt == qs) {  // diagonal tile: causal mask (raw units)
#pragma unroll
      for (int t16 = 0; t16 < 4; t16++)
#pragma unroll
        for (int r = 0; r < 4; r++)
          if (t16 * 16 + g * 4 + r > qrl) S[t16][r] = -3e38f;
    }
    float mx = fmaxf(fmaxf(fmaxf(S[0][0], S[0][1]), fmaxf(S[0][2], S[0][3])),
                     fmaxf(fmaxf(S[1][0], S[1][1]), fmaxf(S[1][2], S[1][3])));
    mx = fmaxf(mx, fmaxf(fmaxf(fmaxf(S[2][0], S[2][1]), fmaxf(S[2][2], S[2][3])),
                         fmaxf(fmaxf(S[3][0], S[3][1]), fmaxf(S[3][2], S[3][3]))));
    mx = fmaxf(mx, __shfl_xor(mx, 16));
    mx = fmaxf(mx, __shfl_xor(mx, 32));
    // defer-max: only rescale when the max has grown by >40 raw (~2^7.2 in P)
    if (!__all(mx - m_s <= 40.f)) {
      const float mnew = fmaxf(m_s, mx);
      const float alpha = fastexp2((m_s - mnew) * sc);
      m_s = mnew;
      l_s *= alpha;
#pragma unroll
      for (int t = 0; t < 4; t++)
#pragma unroll
        for (int r = 0; r < 4; r++) O[t][r] *= alpha;
    }
    const float msc = m_s * sc;
    float p[16];
#pragma unroll
    for (int t16 = 0; t16 < 4; t16++)
#pragma unroll
      for (int r = 0; r < 4; r++) p[t16 * 4 + r] = fastexp2(fmaf(S[t16][r], sc, -msc));
    float ps = 0.f;
#pragma unroll
    for (int i = 0; i < 16; i++) ps += p[i];
    ps += __shfl_xor(ps, 16);
    ps += __shfl_xor(ps, 32);
    l_s += ps;

    // pack P to bf16: c[t16] = keys t16*16 + g*4 + {0..3} for query l15
    // == EXACTLY the B-fragment (col=l15, k=g*4+j) of mfma_f32_16x16x16_bf16.
#pragma unroll
    for (int t16 = 0; t16 < 4; t16++) {
      union { u32 u[2]; s16x4 v; } pbv;
      pbv.u[0] = cvtpk(p[t16 * 4 + 0], p[t16 * 4 + 1]);
      pbv.u[1] = cvtpk(p[t16 * 4 + 2], p[t16 * 4 + 3]);
#pragma unroll
      for (int t = 0; t < 4; t++) {
        int hd = t * 16 + l15;
        int bp = (hd * 128 + t16 * 32 + g * 8) ^ ((hd & 7) << 4);
        s16x4 vf = *(const s16x4*)((const char*)Vs[cur] + bp);
        O[t] = __builtin_amdgcn_mfma_f32_16x16x16bf16_1k(vf, pbv.v, O[t], 0, 0, 0);
      }
    }
    __syncthreads();
    cur ^= 1;
  }

  const float inv = 1.0f / l_s;
  const size_t row = (size_t)(b * T_SEQ + qs * 64 + w * 16 + l15);
#pragma unroll
  for (int t = 0; t < 4; t++)
#pragma unroll
    for (int pr = 0; pr < 2; pr++) {
      u32 pk = cvtpk(O[t][pr * 2 + 0] * inv, O[t][pr * 2 + 1] * inv);
      *(u32*)&attn[row * D_MODEL + h * HDIM + t * 16 + g * 4 + pr * 2] = pk;
    }
}

extern "C" void kernel_launch(void* const* d_in, const int* in_sizes, int n_in,
                              void* d_out, int out_size, void* d_ws, size_t ws_size,
                              hipStream_t stream) {
  const float* x = (const float*)d_in[0];
  const float* w_qkv = (const float*)d_in[1];
  const float* w_proj = (const float*)d_in[2];
  float* out = (float*)d_out;
  char* ws = (char*)d_ws;
  const size_t MB = (size_t)1 << 20;
  if (ws_size < 56 * MB) return;  // need 56 MB scratch
  u16* xb = (u16*)(ws + 0);            // 8 MB  [4096][1024] bf16
  u16* wqkvT = (u16*)(ws + 8 * MB);    // 6 MB  [3072][1024] bf16
  u16* wprojT = (u16*)(ws + 14 * MB);  // 2 MB  [1024][1024] bf16
  u16* qkv = (u16*)(ws + 16 * MB);     // 24 MB [4096][3072] bf16
  u16* vT = (u16*)(ws + 40 * MB);      // 8 MB  [32*64][2048] bf16
  u16* attn = (u16*)(ws + 48 * MB);    // 8 MB  [4096][1024] bf16

  convert_bf16_kernel<<<4096, 256, 0, stream>>>(x, xb, (B_SZ * T_SEQ * D_MODEL) / 4);
  transpose_convert<<<dim3(96, 32), dim3(32, 8), 0, stream>>>(w_qkv, wqkvT, D_MODEL, QKV_P);
  transpose_convert<<<dim3(32, 32), dim3(32, 8), 0, stream>>>(w_proj, wprojT, D_MODEL, D_MODEL);
  gemm_bt<0><<<dim3(QKV_P / 128, (B_SZ * T_SEQ) / 128), 256, 0, stream>>>(
      xb, wqkvT, qkv, B_SZ * T_SEQ, QKV_P, D_MODEL);
  transpose_v<<<dim3(T_SEQ / 32, B_SZ * NHEADS * 2), dim3(32, 8), 0, stream>>>(qkv, vT);
  flash_attn<<<1024, 256, 0, stream>>>(qkv, vT, attn);
  gemm_bt<1><<<dim3(D_MODEL / 128, (B_SZ * T_SEQ) / 128), 256, 0, stream>>>(
      attn, wprojT, out, B_SZ * T_SEQ, D_MODEL, D_MODEL);
}

// Round 10
// 114.722 us; speedup vs baseline: 1.2894x; 1.1152x over previous
//
#include <hip/hip_runtime.h>
#include <stdint.h>

#define B_SZ 2
#define T_SEQ 2048
#define D_MODEL 1024
#define NHEADS 16
#define HDIM 64
#define QKV_P (3 * D_MODEL) /* 3072 */

typedef unsigned short u16;
typedef uint32_t u32;
typedef __attribute__((ext_vector_type(4))) float f32x4;
typedef __attribute__((ext_vector_type(8))) short s16x8;
typedef __attribute__((ext_vector_type(4))) short s16x4;

__device__ __forceinline__ u16 f2bf(float f) {
  union { float f; uint32_t u; } v; v.f = f;
  uint32_t r = v.u + 0x7fffu + ((v.u >> 16) & 1u);
  return (u16)(r >> 16);
}

__device__ __forceinline__ float fastexp2(float x) {
  float r;
  asm volatile("v_exp_f32 %0, %1" : "=v"(r) : "v"(x));
  return r;
}

__device__ __forceinline__ u32 cvtpk(float lo, float hi) {
  u32 r;
  asm volatile("v_cvt_pk_bf16_f32 %0, %1, %2" : "=v"(r) : "v"(lo), "v"(hi));
  return r;
}

__device__ __forceinline__ void async16(const void* g, void* l) {
  __builtin_amdgcn_global_load_lds((const __attribute__((address_space(1))) void*)g,
                                   (__attribute__((address_space(3))) void*)l,
                                   16, 0, 0);
}

// ---------------- merged prep: x->bf16, w_qkv^T->bf16, w_proj^T->bf16 ----------------
__global__ __launch_bounds__(256) void prep(const float* __restrict__ x,
                                            const float* __restrict__ wq,
                                            const float* __restrict__ wp,
                                            u16* __restrict__ xb,
                                            u16* __restrict__ wqkvT,
                                            u16* __restrict__ wprojT) {
  const int bid = blockIdx.x, tid = threadIdx.x;
  if (bid < 4096) {  // convert x: 4096 blocks x 256 thr x 4 floats = 4.19M elems
    int i = bid * 256 + tid;
    float4 v = ((const float4*)x)[i];
    ushort4 o;
    o.x = f2bf(v.x); o.y = f2bf(v.y); o.z = f2bf(v.z); o.w = f2bf(v.w);
    ((ushort4*)xb)[i] = o;
    return;
  }
  __shared__ float tile[32][33];
  const float* in; u16* outp; int C, bx, by;
  if (bid < 4096 + 3072) {
    int bb = bid - 4096; in = wq; outp = wqkvT; C = 3072; bx = bb % 96; by = bb / 96;
  } else {
    int bb = bid - 7168; in = wp; outp = wprojT; C = 1024; bx = bb % 32; by = bb / 32;
  }
  const int tx = tid & 31, ty = tid >> 5;
  const int c0 = bx * 32, r0 = by * 32;
#pragma unroll
  for (int i = 0; i < 4; i++)
    tile[ty + i * 8][tx] = in[(size_t)(r0 + ty + i * 8) * C + c0 + tx];
  __syncthreads();
#pragma unroll
  for (int i = 0; i < 4; i++)
    outp[(size_t)(c0 + ty + i * 8) * D_MODEL + r0 + tx] = f2bf(tile[tx][ty + i * 8]);
}

// ---------------- m97-style bf16 GEMM + prefetch dbuf: C[M,N] = A[M,K] * BT[N,K]^T ----
// VFUSE: blocks with bn>=16 (cols 2048..3071 = the V third of qkv) write their C tile
// TRANSPOSED directly into vT[b*1024 + h*64+hd][t] and skip the qkv write.
template <int F32OUT, int VFUSE>
__global__ __launch_bounds__(256) void gemm_bt(const u16* __restrict__ A,
                                               const u16* __restrict__ BT,
                                               void* __restrict__ Cout,
                                               u16* __restrict__ vTout,
                                               int M, int N, int K) {
  __shared__ u16 As[2][128 * 32];
  __shared__ u16 Bs[2][128 * 32];
  const int tid = threadIdx.x;
  const int lane = tid & 63, w = tid >> 6;
  const int l15 = lane & 15, g = lane >> 4;
  const int wr = w >> 1, wc = w & 1;
  const int bn = blockIdx.x, bm = blockIdx.y;
  const u16* Ab = A + (size_t)bm * 128 * K;
  const u16* Bb = BT + (size_t)bn * 128 * K;
  f32x4 acc[4][4];
#pragma unroll
  for (int i = 0; i < 4; i++)
#pragma unroll
    for (int j = 0; j < 4; j++) acc[i][j] = (f32x4){0.f, 0.f, 0.f, 0.f};
  const int c0 = tid, c1 = tid + 256;

#define GSTAGE(buf, kt_)                                                          \
  do {                                                                            \
    async16(Ab + (size_t)(c0 >> 2) * K + (kt_) + (c0 & 3) * 8, (char*)As[buf] + c0 * 16); \
    async16(Ab + (size_t)(c1 >> 2) * K + (kt_) + (c1 & 3) * 8, (char*)As[buf] + c1 * 16); \
    async16(Bb + (size_t)(c0 >> 2) * K + (kt_) + (c0 & 3) * 8, (char*)Bs[buf] + c0 * 16); \
    async16(Bb + (size_t)(c1 >> 2) * K + (kt_) + (c1 & 3) * 8, (char*)Bs[buf] + c1 * 16); \
  } while (0)

  GSTAGE(0, 0);
  int cur = 0;
  for (int kt = 0; kt < K; kt += 32) {
    if (kt + 32 < K) {
      GSTAGE(cur ^ 1, kt + 32);
      asm volatile("s_waitcnt vmcnt(4)" ::: "memory");  // current tile's 4 loads done
    } else {
      asm volatile("s_waitcnt vmcnt(0)" ::: "memory");
    }
    __syncthreads();
    s16x8 af[4], bfr[4];
#pragma unroll
    for (int i = 0; i < 4; i++)
      af[i] = *(const s16x8*)(As[cur] + (wr * 64 + i * 16 + l15) * 32 + g * 8);
#pragma unroll
    for (int j = 0; j < 4; j++)
      bfr[j] = *(const s16x8*)(Bs[cur] + (wc * 64 + j * 16 + l15) * 32 + g * 8);
#pragma unroll
    for (int i = 0; i < 4; i++)
#pragma unroll
      for (int j = 0; j < 4; j++)
        acc[i][j] = __builtin_amdgcn_mfma_f32_16x16x32_bf16(af[i], bfr[j], acc[i][j], 0, 0, 0);
    __syncthreads();
    cur ^= 1;
  }

  if (VFUSE && bn >= 16) {
    // V third: write transposed into vT[b*1024 + hh][t]; lane holds 4 consecutive t
    const int bloc = bm >> 4;
    const int tb = bm * 128 + wr * 64 - bloc * T_SEQ;
#pragma unroll
    for (int i = 0; i < 4; i++) {
      const int tl = tb + i * 16 + g * 4;
#pragma unroll
      for (int j = 0; j < 4; j++) {
        const int hh = bn * 128 + wc * 64 + j * 16 + l15 - 2048;
        uint2 pk;
        pk.x = cvtpk(acc[i][j][0], acc[i][j][1]);
        pk.y = cvtpk(acc[i][j][2], acc[i][j][3]);
        *(uint2*)&vTout[(size_t)(bloc * 1024 + hh) * T_SEQ + tl] = pk;
      }
    }
    return;
  }
#pragma unroll
  for (int i = 0; i < 4; i++) {
    const int row0 = bm * 128 + wr * 64 + i * 16 + g * 4;
#pragma unroll
    for (int j = 0; j < 4; j++) {
      const int col = bn * 128 + wc * 64 + j * 16 + l15;
#pragma unroll
      for (int r = 0; r < 4; r++) {
        if (F32OUT)
          ((float*)Cout)[(size_t)(row0 + r) * N + col] = acc[i][j][r];
        else
          ((u16*)Cout)[(size_t)(row0 + r) * N + col] = f2bf(acc[i][j][r]);
      }
    }
  }
}

// ---------------- causal flash attention v9 (unchanged from r9) ----------------
__global__ __launch_bounds__(256, 3) void flash_attn(const u16* __restrict__ qkv,
                                                     const u16* __restrict__ vT,
                                                     u16* __restrict__ attn) {
  __shared__ u16 Ks[2][64 * 64];  // [key][hd], XOR-swizzled
  __shared__ u16 Vs[2][64 * 64];  // [hd][key], XOR-swizzled
  const int tid = threadIdx.x;
  const int lane = tid & 63, w = tid >> 6;
  const int l15 = lane & 15, g = lane >> 4;
  const int id = blockIdx.x;
  const int bh = ((id & 7) << 2) | ((id >> 3) & 3);  // 4 heads per XCD
  const int qs = 31 - (id >> 5);                     // 64-row strip, heavy-first
  const int b = bh >> 4, h = bh & 15;

  const size_t qrow = (size_t)(b * T_SEQ + qs * 64 + w * 16 + l15);
  s16x8 qf[2];
  qf[0] = *(const s16x8*)(qkv + qrow * QKV_P + h * HDIM + 0 * 32 + g * 8);
  qf[1] = *(const s16x8*)(qkv + qrow * QKV_P + h * HDIM + 1 * 32 + g * 8);

  f32x4 O[4];
#pragma unroll
  for (int t = 0; t < 4; t++) O[t] = (f32x4){0.f, 0.f, 0.f, 0.f};
  float m_s = -1e30f, l_s = 0.f;
  const int qrl = w * 16 + l15;
  const float sc = 0.18033688011112042f;  // (1/sqrt(64)) * log2(e)

#define STAGE(buf, kvt_)                                                                     \
  do {                                                                                       \
    _Pragma("unroll") for (int i_ = 0; i_ < 2; i_++) {                                       \
      int o_ = (tid + i_ * 256) * 16;                                                        \
      int lo_ = o_ ^ (((o_ >> 7) & 7) << 4);                                                 \
      int row_ = lo_ >> 7;                                                                   \
      int byt_ = lo_ & 127;                                                                  \
      async16(qkv + (size_t)(b * T_SEQ + (kvt_) * 64 + row_) * QKV_P + D_MODEL + h * HDIM +  \
                  (byt_ >> 1),                                                               \
              (char*)Ks[buf] + o_);                                                          \
      async16(vT + (size_t)(bh * HDIM + row_) * T_SEQ + (kvt_) * 64 + (byt_ >> 1),           \
              (char*)Vs[buf] + o_);                                                          \
    }                                                                                        \
  } while (0)

  STAGE(0, 0);
  int cur = 0;
  const int nt = qs + 1;
  for (int kvt = 0; kvt < nt; ++kvt) {
    if (kvt < qs) {
      STAGE(cur ^ 1, kvt + 1);
      asm volatile("s_waitcnt vmcnt(4)" ::: "memory");
    } else {
      asm volatile("s_waitcnt vmcnt(0)" ::: "memory");
    }
    __syncthreads();

    f32x4 S[4];
#pragma unroll
    for (int t16 = 0; t16 < 4; t16++) S[t16] = (f32x4){0.f, 0.f, 0.f, 0.f};
#pragma unroll
    for (int t16 = 0; t16 < 4; t16++)
#pragma unroll
      for (int kk = 0; kk < 2; kk++) {
        int key = t16 * 16 + l15;
        int bp = (key * 128 + kk * 64 + g * 16) ^ ((key & 7) << 4);
        s16x8 kf = *(const s16x8*)((const char*)Ks[cur] + bp);
        S[t16] = __builtin_amdgcn_mfma_f32_16x16x32_bf16(kf, qf[kk], S[t16], 0, 0, 0);
      }

    if (kvt == qs) {
#pragma unroll
      for (int t16 = 0; t16 < 4; t16++)
#pragma unroll
        for (int r = 0; r < 4; r++)
          if (t16 * 16 + g * 4 + r > qrl) S[t16][r] = -3e38f;
    }
    float mx = fmaxf(fmaxf(fmaxf(S[0][0], S[0][1]), fmaxf(S[0][2], S[0][3])),
                     fmaxf(fmaxf(S[1][0], S[1][1]), fmaxf(S[1][2], S[1][3])));
    mx = fmaxf(mx, fmaxf(fmaxf(fmaxf(S[2][0], S[2][1]), fmaxf(S[2][2], S[2][3])),
                         fmaxf(fmaxf(S[3][0], S[3][1]), fmaxf(S[3][2], S[3][3]))));
    mx = fmaxf(mx, __shfl_xor(mx, 16));
    mx = fmaxf(mx, __shfl_xor(mx, 32));
    if (!__all(mx - m_s <= 40.f)) {
      const float mnew = fmaxf(m_s, mx);
      const float alpha = fastexp2((m_s - mnew) * sc);
      m_s = mnew;
      l_s *= alpha;
#pragma unroll
      for (int t = 0; t < 4; t++)
#pragma unroll
        for (int r = 0; r < 4; r++) O[t][r] *= alpha;
    }
    const float msc = m_s * sc;
    float p[16];
#pragma unroll
    for (int t16 = 0; t16 < 4; t16++)
#pragma unroll
      for (int r = 0; r < 4; r++) p[t16 * 4 + r] = fastexp2(fmaf(S[t16][r], sc, -msc));
    float ps = 0.f;
#pragma unroll
    for (int i = 0; i < 16; i++) ps += p[i];
    ps += __shfl_xor(ps, 16);
    ps += __shfl_xor(ps, 32);
    l_s += ps;

#pragma unroll
    for (int t16 = 0; t16 < 4; t16++) {
      union { u32 u[2]; s16x4 v; } pbv;
      pbv.u[0] = cvtpk(p[t16 * 4 + 0], p[t16 * 4 + 1]);
      pbv.u[1] = cvtpk(p[t16 * 4 + 2], p[t16 * 4 + 3]);
#pragma unroll
      for (int t = 0; t < 4; t++) {
        int hd = t * 16 + l15;
        int bp = (hd * 128 + t16 * 32 + g * 8) ^ ((hd & 7) << 4);
        s16x4 vf = *(const s16x4*)((const char*)Vs[cur] + bp);
        O[t] = __builtin_amdgcn_mfma_f32_16x16x16bf16_1k(vf, pbv.v, O[t], 0, 0, 0);
      }
    }
    __syncthreads();
    cur ^= 1;
  }

  const float inv = 1.0f / l_s;
  const size_t row = (size_t)(b * T_SEQ + qs * 64 + w * 16 + l15);
#pragma unroll
  for (int t = 0; t < 4; t++)
#pragma unroll
    for (int pr = 0; pr < 2; pr++) {
      u32 pk = cvtpk(O[t][pr * 2 + 0] * inv, O[t][pr * 2 + 1] * inv);
      *(u32*)&attn[row * D_MODEL + h * HDIM + t * 16 + g * 4 + pr * 2] = pk;
    }
}

extern "C" void kernel_launch(void* const* d_in, const int* in_sizes, int n_in,
                              void* d_out, int out_size, void* d_ws, size_t ws_size,
                              hipStream_t stream) {
  const float* x = (const float*)d_in[0];
  const float* w_qkv = (const float*)d_in[1];
  const float* w_proj = (const float*)d_in[2];
  float* out = (float*)d_out;
  char* ws = (char*)d_ws;
  const size_t MB = (size_t)1 << 20;
  if (ws_size < 56 * MB) return;  // need 56 MB scratch
  u16* xb = (u16*)(ws + 0);            // 8 MB  [4096][1024] bf16
  u16* wqkvT = (u16*)(ws + 8 * MB);    // 6 MB  [3072][1024] bf16
  u16* wprojT = (u16*)(ws + 14 * MB);  // 2 MB  [1024][1024] bf16
  u16* qkv = (u16*)(ws + 16 * MB);     // 24 MB [4096][3072] bf16 (V third unused)
  u16* vT = (u16*)(ws + 40 * MB);      // 8 MB  [2*1024][2048] bf16
  u16* attn = (u16*)(ws + 48 * MB);    // 8 MB  [4096][1024] bf16

  prep<<<8192, 256, 0, stream>>>(x, w_qkv, w_proj, xb, wqkvT, wprojT);
  gemm_bt<0, 1><<<dim3(QKV_P / 128, (B_SZ * T_SEQ) / 128), 256, 0, stream>>>(
      xb, wqkvT, qkv, vT, B_SZ * T_SEQ, QKV_P, D_MODEL);
  flash_attn<<<1024, 256, 0, stream>>>(qkv, vT, attn);
  gemm_bt<1, 0><<<dim3(D_MODEL / 128, (B_SZ * T_SEQ) / 128), 256, 0, stream>>>(
      attn, wprojT, out, nullptr, B_SZ * T_SEQ, D_MODEL, D_MODEL);
}

// Round 11
// 114.194 us; speedup vs baseline: 1.2954x; 1.0046x over previous
//
#include <hip/hip_runtime.h>
#include <stdint.h>

#define B_SZ 2
#define T_SEQ 2048
#define D_MODEL 1024
#define NHEADS 16
#define HDIM 64
#define QKV_P (3 * D_MODEL) /* 3072 */

typedef unsigned short u16;
typedef uint32_t u32;
typedef __attribute__((ext_vector_type(4))) float f32x4;
typedef __attribute__((ext_vector_type(8))) short s16x8;
typedef __attribute__((ext_vector_type(4))) short s16x4;

__device__ __forceinline__ u16 f2bf(float f) {
  union { float f; uint32_t u; } v; v.f = f;
  uint32_t r = v.u + 0x7fffu + ((v.u >> 16) & 1u);
  return (u16)(r >> 16);
}

__device__ __forceinline__ float fastexp2(float x) {
  float r;
  asm volatile("v_exp_f32 %0, %1" : "=v"(r) : "v"(x));
  return r;
}

__device__ __forceinline__ u32 cvtpk(float lo, float hi) {
  u32 r;
  asm volatile("v_cvt_pk_bf16_f32 %0, %1, %2" : "=v"(r) : "v"(lo), "v"(hi));
  return r;
}

__device__ __forceinline__ void async16(const void* g, void* l) {
  __builtin_amdgcn_global_load_lds((const __attribute__((address_space(1))) void*)g,
                                   (__attribute__((address_space(3))) void*)l,
                                   16, 0, 0);
}

// ---------------- merged prep: x->bf16, w_qkv^T->bf16, w_proj^T->bf16 ----------------
__global__ __launch_bounds__(256) void prep(const float* __restrict__ x,
                                            const float* __restrict__ wq,
                                            const float* __restrict__ wp,
                                            u16* __restrict__ xb,
                                            u16* __restrict__ wqkvT,
                                            u16* __restrict__ wprojT) {
  const int bid = blockIdx.x, tid = threadIdx.x;
  if (bid < 4096) {  // convert x: 4096 blocks x 256 thr x 4 floats = 4.19M elems
    int i = bid * 256 + tid;
    float4 v = ((const float4*)x)[i];
    ushort4 o;
    o.x = f2bf(v.x); o.y = f2bf(v.y); o.z = f2bf(v.z); o.w = f2bf(v.w);
    ((ushort4*)xb)[i] = o;
    return;
  }
  __shared__ float tile[32][33];
  const float* in; u16* outp; int C, bx, by;
  if (bid < 4096 + 3072) {
    int bb = bid - 4096; in = wq; outp = wqkvT; C = 3072; bx = bb % 96; by = bb / 96;
  } else {
    int bb = bid - 7168; in = wp; outp = wprojT; C = 1024; bx = bb % 32; by = bb / 32;
  }
  const int tx = tid & 31, ty = tid >> 5;
  const int c0 = bx * 32, r0 = by * 32;
#pragma unroll
  for (int i = 0; i < 4; i++)
    tile[ty + i * 8][tx] = in[(size_t)(r0 + ty + i * 8) * C + c0 + tx];
  __syncthreads();
#pragma unroll
  for (int i = 0; i < 4; i++)
    outp[(size_t)(c0 + ty + i * 8) * D_MODEL + r0 + tx] = f2bf(tile[tx][ty + i * 8]);
}

// ---------------- m97-style bf16 GEMM + prefetch dbuf: C[M,N] = A[M,K] * BT[N,K]^T ----
// VFUSE: blocks with bn>=16 (cols 2048..3071 = the V third of qkv) write their C tile
// TRANSPOSED directly into vT[b*1024 + h*64+hd][t] and skip the qkv write.
template <int F32OUT, int VFUSE>
__global__ __launch_bounds__(256) void gemm_bt(const u16* __restrict__ A,
                                               const u16* __restrict__ BT,
                                               void* __restrict__ Cout,
                                               u16* __restrict__ vTout,
                                               int M, int N, int K) {
  __shared__ u16 As[2][128 * 32];
  __shared__ u16 Bs[2][128 * 32];
  const int tid = threadIdx.x;
  const int lane = tid & 63, w = tid >> 6;
  const int l15 = lane & 15, g = lane >> 4;
  const int wr = w >> 1, wc = w & 1;
  const int bn = blockIdx.x, bm = blockIdx.y;
  const u16* Ab = A + (size_t)bm * 128 * K;
  const u16* Bb = BT + (size_t)bn * 128 * K;
  f32x4 acc[4][4];
#pragma unroll
  for (int i = 0; i < 4; i++)
#pragma unroll
    for (int j = 0; j < 4; j++) acc[i][j] = (f32x4){0.f, 0.f, 0.f, 0.f};
  const int c0 = tid, c1 = tid + 256;

#define GSTAGE(buf, kt_)                                                          \
  do {                                                                            \
    async16(Ab + (size_t)(c0 >> 2) * K + (kt_) + (c0 & 3) * 8, (char*)As[buf] + c0 * 16); \
    async16(Ab + (size_t)(c1 >> 2) * K + (kt_) + (c1 & 3) * 8, (char*)As[buf] + c1 * 16); \
    async16(Bb + (size_t)(c0 >> 2) * K + (kt_) + (c0 & 3) * 8, (char*)Bs[buf] + c0 * 16); \
    async16(Bb + (size_t)(c1 >> 2) * K + (kt_) + (c1 & 3) * 8, (char*)Bs[buf] + c1 * 16); \
  } while (0)

  GSTAGE(0, 0);
  int cur = 0;
  for (int kt = 0; kt < K; kt += 32) {
    if (kt + 32 < K) {
      GSTAGE(cur ^ 1, kt + 32);
      asm volatile("s_waitcnt vmcnt(4)" ::: "memory");  // current tile's 4 loads done
    } else {
      asm volatile("s_waitcnt vmcnt(0)" ::: "memory");
    }
    __syncthreads();
    s16x8 af[4], bfr[4];
#pragma unroll
    for (int i = 0; i < 4; i++)
      af[i] = *(const s16x8*)(As[cur] + (wr * 64 + i * 16 + l15) * 32 + g * 8);
#pragma unroll
    for (int j = 0; j < 4; j++)
      bfr[j] = *(const s16x8*)(Bs[cur] + (wc * 64 + j * 16 + l15) * 32 + g * 8);
#pragma unroll
    for (int i = 0; i < 4; i++)
#pragma unroll
      for (int j = 0; j < 4; j++)
        acc[i][j] = __builtin_amdgcn_mfma_f32_16x16x32_bf16(af[i], bfr[j], acc[i][j], 0, 0, 0);
    __syncthreads();
    cur ^= 1;
  }

  if (VFUSE && bn >= 16) {
    // V third: write transposed into vT[b*1024 + hh][t]; lane holds 4 consecutive t
    const int bloc = bm >> 4;
    const int tb = bm * 128 + wr * 64 - bloc * T_SEQ;
#pragma unroll
    for (int i = 0; i < 4; i++) {
      const int tl = tb + i * 16 + g * 4;
#pragma unroll
      for (int j = 0; j < 4; j++) {
        const int hh = bn * 128 + wc * 64 + j * 16 + l15 - 2048;
        uint2 pk;
        pk.x = cvtpk(acc[i][j][0], acc[i][j][1]);
        pk.y = cvtpk(acc[i][j][2], acc[i][j][3]);
        *(uint2*)&vTout[(size_t)(bloc * 1024 + hh) * T_SEQ + tl] = pk;
      }
    }
    return;
  }
#pragma unroll
  for (int i = 0; i < 4; i++) {
    const int row0 = bm * 128 + wr * 64 + i * 16 + g * 4;
#pragma unroll
    for (int j = 0; j < 4; j++) {
      const int col = bn * 128 + wc * 64 + j * 16 + l15;
#pragma unroll
      for (int r = 0; r < 4; r++) {
        if (F32OUT)
          ((float*)Cout)[(size_t)(row0 + r) * N + col] = acc[i][j][r];
        else
          ((u16*)Cout)[(size_t)(row0 + r) * N + col] = f2bf(acc[i][j][r]);
      }
    }
  }
}

// ---------------- causal flash attention v10 ----------------
// r9 kernel + (a) __launch_bounds__(256,4): 4 blocks/CU resident -> whole 1024-block
// grid co-resident (was 3+1 queued = serialized tail); (b) balanced per-CU strip map:
// CU gets ids {c, c+256, c+512, c+768} -> qs {31-j, 16+j, 15-j, j}, sum 62 for all j
// (monotone map had per-CU sums 48..76 -> 1.58x makespan spread).
__global__ __launch_bounds__(256, 4) void flash_attn(const u16* __restrict__ qkv,
                                                     const u16* __restrict__ vT,
                                                     u16* __restrict__ attn) {
  __shared__ u16 Ks[2][64 * 64];  // [key][hd], XOR-swizzled
  __shared__ u16 Vs[2][64 * 64];  // [hd][key], XOR-swizzled
  const int tid = threadIdx.x;
  const int lane = tid & 63, w = tid >> 6;
  const int l15 = lane & 15, g = lane >> 4;
  const int id = blockIdx.x;
  const int bh = ((id & 7) << 2) | ((id >> 3) & 3);  // 4 heads per XCD
  const int j = (id >> 5) & 7, k4 = (id >> 8) & 3;   // balanced strip map
  const int qs = (k4 == 0) ? (31 - j) : (k4 == 1) ? (16 + j) : (k4 == 2) ? (15 - j) : j;
  const int b = bh >> 4, h = bh & 15;

  const size_t qrow = (size_t)(b * T_SEQ + qs * 64 + w * 16 + l15);
  s16x8 qf[2];
  qf[0] = *(const s16x8*)(qkv + qrow * QKV_P + h * HDIM + 0 * 32 + g * 8);
  qf[1] = *(const s16x8*)(qkv + qrow * QKV_P + h * HDIM + 1 * 32 + g * 8);

  f32x4 O[4];
#pragma unroll
  for (int t = 0; t < 4; t++) O[t] = (f32x4){0.f, 0.f, 0.f, 0.f};
  float m_s = -1e30f, l_s = 0.f;
  const int qrl = w * 16 + l15;
  const float sc = 0.18033688011112042f;  // (1/sqrt(64)) * log2(e)

#define STAGE(buf, kvt_)                                                                     \
  do {                                                                                       \
    _Pragma("unroll") for (int i_ = 0; i_ < 2; i_++) {                                       \
      int o_ = (tid + i_ * 256) * 16;                                                        \
      int lo_ = o_ ^ (((o_ >> 7) & 7) << 4);                                                 \
      int row_ = lo_ >> 7;                                                                   \
      int byt_ = lo_ & 127;                                                                  \
      async16(qkv + (size_t)(b * T_SEQ + (kvt_) * 64 + row_) * QKV_P + D_MODEL + h * HDIM +  \
                  (byt_ >> 1),                                                               \
              (char*)Ks[buf] + o_);                                                          \
      async16(vT + (size_t)(bh * HDIM + row_) * T_SEQ + (kvt_) * 64 + (byt_ >> 1),           \
              (char*)Vs[buf] + o_);                                                          \
    }                                                                                        \
  } while (0)

  STAGE(0, 0);
  int cur = 0;
  const int nt = qs + 1;
  for (int kvt = 0; kvt < nt; ++kvt) {
    if (kvt < qs) {
      STAGE(cur ^ 1, kvt + 1);
      asm volatile("s_waitcnt vmcnt(4)" ::: "memory");
    } else {
      asm volatile("s_waitcnt vmcnt(0)" ::: "memory");
    }
    __syncthreads();

    f32x4 S[4];
#pragma unroll
    for (int t16 = 0; t16 < 4; t16++) S[t16] = (f32x4){0.f, 0.f, 0.f, 0.f};
#pragma unroll
    for (int t16 = 0; t16 < 4; t16++)
#pragma unroll
      for (int kk = 0; kk < 2; kk++) {
        int key = t16 * 16 + l15;
        int bp = (key * 128 + kk * 64 + g * 16) ^ ((key & 7) << 4);
        s16x8 kf = *(const s16x8*)((const char*)Ks[cur] + bp);
        S[t16] = __builtin_amdgcn_mfma_f32_16x16x32_bf16(kf, qf[kk], S[t16], 0, 0, 0);
      }

    if (kvt == qs) {
#pragma unroll
      for (int t16 = 0; t16 < 4; t16++)
#pragma unroll
        for (int r = 0; r < 4; r++)
          if (t16 * 16 + g * 4 + r > qrl) S[t16][r] = -3e38f;
    }
    float mx = fmaxf(fmaxf(fmaxf(S[0][0], S[0][1]), fmaxf(S[0][2], S[0][3])),
                     fmaxf(fmaxf(S[1][0], S[1][1]), fmaxf(S[1][2], S[1][3])));
    mx = fmaxf(mx, fmaxf(fmaxf(fmaxf(S[2][0], S[2][1]), fmaxf(S[2][2], S[2][3])),
                         fmaxf(fmaxf(S[3][0], S[3][1]), fmaxf(S[3][2], S[3][3]))));
    mx = fmaxf(mx, __shfl_xor(mx, 16));
    mx = fmaxf(mx, __shfl_xor(mx, 32));
    if (!__all(mx - m_s <= 40.f)) {
      const float mnew = fmaxf(m_s, mx);
      const float alpha = fastexp2((m_s - mnew) * sc);
      m_s = mnew;
      l_s *= alpha;
#pragma unroll
      for (int t = 0; t < 4; t++)
#pragma unroll
        for (int r = 0; r < 4; r++) O[t][r] *= alpha;
    }
    const float msc = m_s * sc;
    float p[16];
#pragma unroll
    for (int t16 = 0; t16 < 4; t16++)
#pragma unroll
      for (int r = 0; r < 4; r++) p[t16 * 4 + r] = fastexp2(fmaf(S[t16][r], sc, -msc));
    float ps = 0.f;
#pragma unroll
    for (int i = 0; i < 16; i++) ps += p[i];
    ps += __shfl_xor(ps, 16);
    ps += __shfl_xor(ps, 32);
    l_s += ps;

#pragma unroll
    for (int t16 = 0; t16 < 4; t16++) {
      union { u32 u[2]; s16x4 v; } pbv;
      pbv.u[0] = cvtpk(p[t16 * 4 + 0], p[t16 * 4 + 1]);
      pbv.u[1] = cvtpk(p[t16 * 4 + 2], p[t16 * 4 + 3]);
#pragma unroll
      for (int t = 0; t < 4; t++) {
        int hd = t * 16 + l15;
        int bp = (hd * 128 + t16 * 32 + g * 8) ^ ((hd & 7) << 4);
        s16x4 vf = *(const s16x4*)((const char*)Vs[cur] + bp);
        O[t] = __builtin_amdgcn_mfma_f32_16x16x16bf16_1k(vf, pbv.v, O[t], 0, 0, 0);
      }
    }
    __syncthreads();
    cur ^= 1;
  }

  const float inv = 1.0f / l_s;
  const size_t row = (size_t)(b * T_SEQ + qs * 64 + w * 16 + l15);
#pragma unroll
  for (int t = 0; t < 4; t++)
#pragma unroll
    for (int pr = 0; pr < 2; pr++) {
      u32 pk = cvtpk(O[t][pr * 2 + 0] * inv, O[t][pr * 2 + 1] * inv);
      *(u32*)&attn[row * D_MODEL + h * HDIM + t * 16 + g * 4 + pr * 2] = pk;
    }
}

extern "C" void kernel_launch(void* const* d_in, const int* in_sizes, int n_in,
                              void* d_out, int out_size, void* d_ws, size_t ws_size,
                              hipStream_t stream) {
  const float* x = (const float*)d_in[0];
  const float* w_qkv = (const float*)d_in[1];
  const float* w_proj = (const float*)d_in[2];
  float* out = (float*)d_out;
  char* ws = (char*)d_ws;
  const size_t MB = (size_t)1 << 20;
  if (ws_size < 56 * MB) return;  // need 56 MB scratch
  u16* xb = (u16*)(ws + 0);            // 8 MB  [4096][1024] bf16
  u16* wqkvT = (u16*)(ws + 8 * MB);    // 6 MB  [3072][1024] bf16
  u16* wprojT = (u16*)(ws + 14 * MB);  // 2 MB  [1024][1024] bf16
  u16* qkv = (u16*)(ws + 16 * MB);     // 24 MB [4096][3072] bf16 (V third unused)
  u16* vT = (u16*)(ws + 40 * MB);      // 8 MB  [2*1024][2048] bf16
  u16* attn = (u16*)(ws + 48 * MB);    // 8 MB  [4096][1024] bf16

  prep<<<8192, 256, 0, stream>>>(x, w_qkv, w_proj, xb, wqkvT, wprojT);
  gemm_bt<0, 1><<<dim3(QKV_P / 128, (B_SZ * T_SEQ) / 128), 256, 0, stream>>>(
      xb, wqkvT, qkv, vT, B_SZ * T_SEQ, QKV_P, D_MODEL);
  flash_attn<<<1024, 256, 0, stream>>>(qkv, vT, attn);
  gemm_bt<1, 0><<<dim3(D_MODEL / 128, (B_SZ * T_SEQ) / 128), 256, 0, stream>>>(
      attn, wprojT, out, nullptr, B_SZ * T_SEQ, D_MODEL, D_MODEL);
}